// Round 6
// baseline (1330.984 us; speedup 1.0000x reference)
//
#include <hip/hip_runtime.h>
#include <hip/hip_bf16.h>

#define BQ 16
#define CH 192
#define HH 64
#define WW 64
#define HWSZ 4096
#define NPIX 65536
#define NHEADS 6
#define HDIM 32
#define NPAIR 96
#define KMAXR 48
#define HID 768

typedef __hip_bfloat16 bf16;
typedef __attribute__((ext_vector_type(8))) short short8;
typedef __attribute__((ext_vector_type(4))) float floatx4;

static __device__ __forceinline__ float b2f(bf16 v) { return __bfloat162float(v); }
static __device__ __forceinline__ bf16 f2b(float v) { return __float2bfloat16(v); }

static __device__ __forceinline__ float4 ld4(const float* p) { return *(const float4*)p; }
static __device__ __forceinline__ float4 ld4(const bf16* p) {
  uint2 u = *(const uint2*)p;
  return make_float4(__uint_as_float(u.x << 16), __uint_as_float(u.x & 0xffff0000u),
                     __uint_as_float(u.y << 16), __uint_as_float(u.y & 0xffff0000u));
}

template <int ACT>
static __device__ __forceinline__ float actf(float v) {
  if (ACT == 1) return v / (1.f + expf(-v));                               // silu
  if (ACT == 2) return (v > 0.f) ? v + 1.f : expf(v);                      // elu+1
  if (ACT == 3) return 0.5f * v * (1.f + erff(v * 0.70710678118654752f));  // gelu
  return v;
}
static __device__ __forceinline__ void stv(float* p, float v) { *p = v; }
static __device__ __forceinline__ void stv(bf16* p, float v) { *p = __float2bfloat16(v); }

// ---------------- transpose NCHW -> NHWC (fp32) ----------------
__global__ __launch_bounds__(256) void k_transpose_in(const float* __restrict__ in,
                                                      float* __restrict__ out) {
  __shared__ float tile[32][33];
  int c0 = blockIdx.x * 32, hw0 = blockIdx.y * 32, b = blockIdx.z;
  int tx = threadIdx.x, ty = threadIdx.y;
  const float* src = in + (size_t)b * CH * HWSZ;
  #pragma unroll
  for (int j = 0; j < 32; j += 8)
    tile[ty + j][tx] = src[(size_t)(c0 + ty + j) * HWSZ + hw0 + tx];
  __syncthreads();
  float* dst = out + (size_t)b * HWSZ * CH;
  #pragma unroll
  for (int j = 0; j < 32; j += 8)
    dst[(size_t)(hw0 + ty + j) * CH + c0 + tx] = tile[tx][ty + j];
}

// ---------------- transpose NHWC -> NCHW (fp32) ----------------
__global__ __launch_bounds__(256) void k_transpose_out(const float* __restrict__ in,
                                                       float* __restrict__ out) {
  __shared__ float tile[32][33];
  int c0 = blockIdx.x * 32, hw0 = blockIdx.y * 32, b = blockIdx.z;
  int tx = threadIdx.x, ty = threadIdx.y;
  const float* src = in + (size_t)b * HWSZ * CH;
  #pragma unroll
  for (int j = 0; j < 32; j += 8)
    tile[ty + j][tx] = src[(size_t)(hw0 + ty + j) * CH + c0 + tx];
  __syncthreads();
  float* dst = out + (size_t)b * CH * HWSZ;
  #pragma unroll
  for (int j = 0; j < 32; j += 8)
    dst[(size_t)(c0 + ty + j) * HWSZ + hw0 + tx] = tile[tx][ty + j];
}

// ---------------- RoPE tables, layout [pair][hw] ----------------
__global__ __launch_bounds__(256) void k_rope(float* __restrict__ cosT, float* __restrict__ sinT) {
  int i = blockIdx.x * 256 + threadIdx.x;
  if (i >= NPAIR * HWSZ) return;
  int hw = i & (HWSZ - 1);
  int p = i >> 12;
  int h = hw >> 6, w = hw & 63;
  int j = (p < KMAXR) ? p : p - KMAXR;
  float theta = powf(10000.f, -(float)j / (float)KMAXR);
  float pos = (p < KMAXR) ? (float)h : (float)w;
  float ang = pos * theta;
  cosT[i] = cosf(ang);
  sinT[i] = sinf(ang);
}

// ---------------- fused dwconv(residual) + LayerNorm ----------------
// block = 4 pixels x 48 channel-groups (4ch each), 192 threads.
template <typename TI>
__global__ __launch_bounds__(192) void k_cpe_ln(const TI* __restrict__ in,
                                                const float* __restrict__ w,
                                                const float* __restrict__ bias,
                                                const float* __restrict__ g,
                                                const float* __restrict__ bt,
                                                float* __restrict__ x1o,
                                                bf16* __restrict__ yo) {
  __shared__ float sred[192], ssred[192];
  int t = threadIdx.x;
  int cg = t % 48, pl = t / 48;
  int pix = blockIdx.x * 4 + pl;
  int hw = pix & (HWSZ - 1);
  int h = hw >> 6, wx = hw & 63;
  int c0 = cg * 4;
  float4 w4[9];
  #pragma unroll
  for (int i = 0; i < 9; i++) w4[i] = ld4(w + c0 * 9 + i * 4);
  float4 bi = ld4(bias + c0);
  float acc0 = bi.x, acc1 = bi.y, acc2 = bi.z, acc3 = bi.w;
  float4 ctr;
  const TI* base = in + (size_t)pix * CH + c0;
  #pragma unroll
  for (int dh = -1; dh <= 1; dh++) {
    #pragma unroll
    for (int dw = -1; dw <= 1; dw++) {
      bool v = ((unsigned)(h + dh) < HH) && ((unsigned)(wx + dw) < WW);
      float4 tv = v ? ld4(base + (dh * WW + dw) * CH) : make_float4(0, 0, 0, 0);
      if (dh == 0 && dw == 0) ctr = tv;
      const int tap = (dh + 1) * 3 + (dw + 1);
      #define WX(j) (((const float*)w4)[(j) * 9 + tap])
      acc0 += tv.x * WX(0);
      acc1 += tv.y * WX(1);
      acc2 += tv.z * WX(2);
      acc3 += tv.w * WX(3);
      #undef WX
    }
  }
  float x0 = ctr.x + acc0, x1 = ctr.y + acc1, x2 = ctr.z + acc2, x3 = ctr.w + acc3;
  *(float4*)&x1o[(size_t)pix * CH + c0] = make_float4(x0, x1, x2, x3);
  sred[t] = x0 + x1 + x2 + x3;
  ssred[t] = x0 * x0 + x1 * x1 + x2 * x2 + x3 * x3;
  __syncthreads();
  float S = 0.f, SS = 0.f;
  int rb = pl * 48;
  #pragma unroll
  for (int i = 0; i < 48; i++) { S += sred[rb + i]; SS += ssred[rb + i]; }
  float mu = S * (1.f / CH);
  float inv = rsqrtf(SS * (1.f / CH) - mu * mu + 1e-5f);
  float4 gg = ld4(g + c0);
  float4 bb = ld4(bt + c0);
  __align__(8) bf16 tmp[4] = {f2b((x0 - mu) * inv * gg.x + bb.x),
                              f2b((x1 - mu) * inv * gg.y + bb.y),
                              f2b((x2 - mu) * inv * gg.z + bb.z),
                              f2b((x3 - mu) * inv * gg.w + bb.w)};
  *(uint2*)&yo[(size_t)pix * CH + c0] = *(uint2*)tmp;
}

// ---------------- vectorized dwconv, bf16 in/out, 4ch per thread, silu ----------------
__global__ __launch_bounds__(256) void k_dwconv4(const bf16* __restrict__ in,
                                                 const float* __restrict__ w,
                                                 const float* __restrict__ bias,
                                                 bf16* __restrict__ out) {
  int id = blockIdx.x * 256 + threadIdx.x;  // NPIX*48
  int cg = id % 48, pix = id / 48;
  int hw = pix & (HWSZ - 1);
  int h = hw >> 6, wx = hw & 63;
  int c0 = cg * 4;
  float4 w4[9];
  #pragma unroll
  for (int i = 0; i < 9; i++) w4[i] = ld4(w + c0 * 9 + i * 4);
  float4 bi = ld4(bias + c0);
  float acc0 = bi.x, acc1 = bi.y, acc2 = bi.z, acc3 = bi.w;
  const bf16* base = in + (size_t)pix * CH + c0;
  #pragma unroll
  for (int dh = -1; dh <= 1; dh++) {
    #pragma unroll
    for (int dw = -1; dw <= 1; dw++) {
      bool v = ((unsigned)(h + dh) < HH) && ((unsigned)(wx + dw) < WW);
      float4 tv = v ? ld4(base + (dh * WW + dw) * CH) : make_float4(0, 0, 0, 0);
      const int tap = (dh + 1) * 3 + (dw + 1);
      #define WX(j) (((const float*)w4)[(j) * 9 + tap])
      acc0 += tv.x * WX(0);
      acc1 += tv.y * WX(1);
      acc2 += tv.z * WX(2);
      acc3 += tv.w * WX(3);
      #undef WX
    }
  }
  bf16* op = out + (size_t)pix * CH + c0;
  acc0 = acc0 / (1.f + expf(-acc0));
  acc1 = acc1 / (1.f + expf(-acc1));
  acc2 = acc2 / (1.f + expf(-acc2));
  acc3 = acc3 / (1.f + expf(-acc3));
  __align__(8) bf16 tmp[4] = {f2b(acc0), f2b(acc1), f2b(acc2), f2b(acc3)};
  *(uint2*)op = *(uint2*)tmp;
}

// ---------------- MFMA bf16 GEMM: tile 128x64, BK=32 ----------------
template <int ACT, int MULA, int RES, typename TO>
__global__ __launch_bounds__(256) void k_gemm(const bf16* __restrict__ A,
                                              const bf16* __restrict__ A2,
                                              const float* __restrict__ Wt,
                                              const float* __restrict__ bias,
                                              const float* __restrict__ Rsd,
                                              TO* __restrict__ Cout,
                                              int M, int N, int K) {
  __shared__ bf16 As[128][40];
  __shared__ bf16 Bs[64][40];
  int t = threadIdx.x;
  int wave = t >> 6, lane = t & 63;
  int quad = lane >> 4, l16 = lane & 15;
  int m0 = blockIdx.x * 128, n0 = blockIdx.y * 64;
  floatx4 acc[2][4] = {};
  for (int k0 = 0; k0 < K; k0 += 32) {
    #pragma unroll
    for (int i = 0; i < 2; i++) {
      int idx = t + i * 256;
      int m = idx >> 2, kk = (idx & 3) * 8;
      const bf16* pa = &A[(size_t)(m0 + m) * K + k0 + kk];
      if (!MULA) {
        *(short8*)&As[m][kk] = *(const short8*)pa;
      } else {
        const bf16* pb = &A2[(size_t)(m0 + m) * K + k0 + kk];
        __align__(16) bf16 tmp[8];
        #pragma unroll
        for (int j = 0; j < 8; j++) tmp[j] = f2b(b2f(pa[j]) * b2f(pb[j]));
        *(short8*)&As[m][kk] = *(const short8*)tmp;
      }
    }
    #pragma unroll
    for (int i = 0; i < 2; i++) {
      int idx = t + i * 256;
      int n = idx >> 3, kk = (idx & 7) * 4;
      float4 v = *(const float4*)&Wt[(size_t)(n0 + n) * K + k0 + kk];
      __align__(8) bf16 tmp[4] = {f2b(v.x), f2b(v.y), f2b(v.z), f2b(v.w)};
      *(uint2*)&Bs[n][kk] = *(uint2*)tmp;
    }
    __syncthreads();
    short8 af[2], bfr[4];
    #pragma unroll
    for (int i = 0; i < 2; i++)
      af[i] = *(const short8*)&As[wave * 32 + i * 16 + l16][quad * 8];
    #pragma unroll
    for (int j = 0; j < 4; j++)
      bfr[j] = *(const short8*)&Bs[j * 16 + l16][quad * 8];
    #pragma unroll
    for (int i = 0; i < 2; i++)
      #pragma unroll
      for (int j = 0; j < 4; j++)
        acc[i][j] = __builtin_amdgcn_mfma_f32_16x16x32_bf16(af[i], bfr[j], acc[i][j], 0, 0, 0);
    __syncthreads();
  }
  #pragma unroll
  for (int i = 0; i < 2; i++) {
    #pragma unroll
    for (int j = 0; j < 4; j++) {
      int n = n0 + j * 16 + l16;
      float bn = bias[n];
      #pragma unroll
      for (int r = 0; r < 4; r++) {
        int m = m0 + wave * 32 + i * 16 + quad * 4 + r;
        float v = actf<ACT>(acc[i][j][r] + bn);
        if (RES) v += Rsd[(size_t)m * N + n];
        stv(&Cout[(size_t)m * N + n], v);
      }
    }
  }
}

// dual-output GEMM: N=384 as two 192 halves; optional fused column-mean of half B.
template <int ACTA, int ACTB, int KMEAN>
__global__ __launch_bounds__(256) void k_gemm_dual(const bf16* __restrict__ A,
                                                   const float* __restrict__ WtA,
                                                   const float* __restrict__ biasA,
                                                   const float* __restrict__ WtB,
                                                   const float* __restrict__ biasB,
                                                   bf16* __restrict__ OutA,
                                                   bf16* __restrict__ OutB,
                                                   float* __restrict__ KM,
                                                   int K) {
  __shared__ bf16 As[128][40];
  __shared__ bf16 Bs[64][40];
  __shared__ float colsum[64];
  int t = threadIdx.x;
  int wave = t >> 6, lane = t & 63;
  int quad = lane >> 4, l16 = lane & 15;
  int m0 = blockIdx.x * 128, n0 = blockIdx.y * 64;
  int half = n0 >= 192;
  int n0l = half ? n0 - 192 : n0;
  const float* Wt = half ? WtB : WtA;
  const float* bias = half ? biasB : biasA;
  bf16* Out = half ? OutB : OutA;
  if (KMEAN && half && t < 64) colsum[t] = 0.f;
  floatx4 acc[2][4] = {};
  for (int k0 = 0; k0 < K; k0 += 32) {
    #pragma unroll
    for (int i = 0; i < 2; i++) {
      int idx = t + i * 256;
      int m = idx >> 2, kk = (idx & 3) * 8;
      *(short8*)&As[m][kk] = *(const short8*)&A[(size_t)(m0 + m) * K + k0 + kk];
    }
    #pragma unroll
    for (int i = 0; i < 2; i++) {
      int idx = t + i * 256;
      int n = idx >> 3, kk = (idx & 7) * 4;
      float4 v = *(const float4*)&Wt[(size_t)(n0l + n) * K + k0 + kk];
      __align__(8) bf16 tmp[4] = {f2b(v.x), f2b(v.y), f2b(v.z), f2b(v.w)};
      *(uint2*)&Bs[n][kk] = *(uint2*)tmp;
    }
    __syncthreads();
    short8 af[2], bfr[4];
    #pragma unroll
    for (int i = 0; i < 2; i++)
      af[i] = *(const short8*)&As[wave * 32 + i * 16 + l16][quad * 8];
    #pragma unroll
    for (int j = 0; j < 4; j++)
      bfr[j] = *(const short8*)&Bs[j * 16 + l16][quad * 8];
    #pragma unroll
    for (int i = 0; i < 2; i++)
      #pragma unroll
      for (int j = 0; j < 4; j++)
        acc[i][j] = __builtin_amdgcn_mfma_f32_16x16x32_bf16(af[i], bfr[j], acc[i][j], 0, 0, 0);
    __syncthreads();
  }
  #pragma unroll
  for (int j = 0; j < 4; j++) {
    int nl = n0l + j * 16 + l16;
    float bn = bias[nl];
    float csum = 0.f;
    #pragma unroll
    for (int i = 0; i < 2; i++) {
      #pragma unroll
      for (int r = 0; r < 4; r++) {
        int m = m0 + wave * 32 + i * 16 + quad * 4 + r;
        float v = half ? actf<ACTB>(acc[i][j][r] + bn) : actf<ACTA>(acc[i][j][r] + bn);
        if (KMEAN && half) csum += v;
        Out[(size_t)m * CH + nl] = f2b(v);
      }
    }
    if (KMEAN && half) atomicAdd(&colsum[j * 16 + l16], csum);
  }
  if (KMEAN && half) {
    __syncthreads();
    if (t < 64) {
      int b = m0 >> 12;
      atomicAdd(&KM[b * CH + n0l + t], colsum[t] * (1.f / 4096.f));
    }
  }
}

// ---------------- kv: fused-rope staging, 512 rows/block, bf16 LDS ----------------
__global__ __launch_bounds__(256) void k_kv(const bf16* __restrict__ k,
                                            const bf16* __restrict__ v,
                                            const float* __restrict__ cosT,
                                            const float* __restrict__ sinT,
                                            float* __restrict__ kv) {
  int bh = blockIdx.x;
  int b = bh / NHEADS, hd = bh % NHEADS;
  int chunk0 = blockIdx.y * 512;
  __shared__ bf16 ks[256][40];
  __shared__ bf16 vs[256][40];
  int t = threadIdx.x;
  int d = t >> 3;
  int e0 = (t & 7) * 4;
  float a0 = 0, a1 = 0, a2 = 0, a3 = 0;
  for (int sub = 0; sub < 2; sub++) {
    int n0 = chunk0 + sub * 256;
    // stage 256 rows: rope(k) and raw v -> bf16 LDS
    #pragma unroll
    for (int it = 0; it < 4; it++) {
      int idx = t + it * 256;            // 0..1023
      int row = idx >> 2, c0 = (idx & 3) * 8;
      int n = n0 + row;
      size_t gi = ((size_t)(b * HWSZ + n)) * CH + hd * HDIM + c0;
      // v: raw copy
      *(short8*)&vs[row][c0] = *(const short8*)&v[gi];
      // k: load 8, rope 4 pairs, pack
      float4 klo = ld4(&k[gi]);
      float4 khi = ld4(&k[gi + 4]);
      int prb = hd * 16 + (c0 >> 1);
      float cs0 = cosT[(size_t)(prb + 0) * HWSZ + n];
      float sn0 = sinT[(size_t)(prb + 0) * HWSZ + n];
      float cs1 = cosT[(size_t)(prb + 1) * HWSZ + n];
      float sn1 = sinT[(size_t)(prb + 1) * HWSZ + n];
      float cs2 = cosT[(size_t)(prb + 2) * HWSZ + n];
      float sn2 = sinT[(size_t)(prb + 2) * HWSZ + n];
      float cs3 = cosT[(size_t)(prb + 3) * HWSZ + n];
      float sn3 = sinT[(size_t)(prb + 3) * HWSZ + n];
      __align__(16) bf16 kt[8];
      kt[0] = f2b(klo.x * cs0 - klo.y * sn0);
      kt[1] = f2b(klo.x * sn0 + klo.y * cs0);
      kt[2] = f2b(klo.z * cs1 - klo.w * sn1);
      kt[3] = f2b(klo.z * sn1 + klo.w * cs1);
      kt[4] = f2b(khi.x * cs2 - khi.y * sn2);
      kt[5] = f2b(khi.x * sn2 + khi.y * cs2);
      kt[6] = f2b(khi.z * cs3 - khi.w * sn3);
      kt[7] = f2b(khi.z * sn3 + khi.w * cs3);
      *(short8*)&ks[row][c0] = *(const short8*)kt;
    }
    __syncthreads();
    #pragma unroll 4
    for (int i = 0; i < 256; i++) {
      float kd = b2f(ks[i][d]);
      float4 vv = ld4(&vs[i][e0]);
      a0 += kd * vv.x;
      a1 += kd * vv.y;
      a2 += kd * vv.z;
      a3 += kd * vv.w;
    }
    __syncthreads();
  }
  float* dst = kv + (size_t)bh * (HDIM * HDIM) + d * HDIM + e0;
  const float sc = 1.f / 4096.f;
  atomicAdd(dst + 0, a0 * sc);
  atomicAdd(dst + 1, a1 * sc);
  atomicAdd(dst + 2, a2 * sc);
  atomicAdd(dst + 3, a3 * sc);
}

// ---------------- attn + fused lepe: out = (q_rope@kv)*z + dwconv(v) ----------------
__global__ __launch_bounds__(256) void k_attn(const bf16* __restrict__ q,
                                              const bf16* __restrict__ vsrc,
                                              const float* __restrict__ kv,
                                              const float* __restrict__ kmean,
                                              const float* __restrict__ cosT,
                                              const float* __restrict__ sinT,
                                              const float* __restrict__ lepw,
                                              const float* __restrict__ lepb,
                                              bf16* __restrict__ attn) {
  int hd = blockIdx.y, b = blockIdx.z;
  int hw = blockIdx.x * 256 + threadIdx.x;
  int bh = b * NHEADS + hd;
  __shared__ float kvs[32][33];
  __shared__ float kms[32];
  __shared__ float wst[9][32];
  __shared__ float lbs[32];
  #pragma unroll
  for (int i = 0; i < 4; i++) {
    int idx = threadIdx.x + i * 256;
    kvs[idx >> 5][idx & 31] = kv[(size_t)bh * 1024 + idx];
  }
  if (threadIdx.x < 32) {
    kms[threadIdx.x] = kmean[b * CH + hd * HDIM + threadIdx.x];
    lbs[threadIdx.x] = lepb[hd * HDIM + threadIdx.x];
  }
  if (threadIdx.x >= 32 && threadIdx.x < 32 + 288) {
    int i = threadIdx.x - 32;
    int e = i & 31, tap = i >> 5;
    wst[tap][e] = lepw[(hd * HDIM + e) * 9 + tap];
  }
  __syncthreads();
  int pix = b * HWSZ + hw;
  int h = hw >> 6, wx = hw & 63;
  const bf16* qp = q + (size_t)pix * CH + hd * HDIM;
  float qv[32];
  #pragma unroll
  for (int i = 0; i < 32; i++) qv[i] = b2f(qp[i]);
  float z = 1e-6f;
  #pragma unroll
  for (int d = 0; d < 32; d++) z += qv[d] * kms[d];
  float o[32] = {};
  #pragma unroll
  for (int p = 0; p < 16; p++) {
    float cs = cosT[(size_t)(hd * 16 + p) * HWSZ + hw];
    float sn = sinT[(size_t)(hd * 16 + p) * HWSZ + hw];
    float re = qv[2 * p], im = qv[2 * p + 1];
    float qr = re * cs - im * sn;
    float qi = re * sn + im * cs;
    #pragma unroll
    for (int e = 0; e < 32; e++)
      o[e] += qr * kvs[2 * p][e] + qi * kvs[2 * p + 1][e];
  }
  float zi = 1.f / z;
  // lepe: depthwise 3x3 on v (this head's 32 channels)
  float le[32];
  #pragma unroll
  for (int e = 0; e < 32; e++) le[e] = lbs[e];
  const bf16* vbase = vsrc + (size_t)pix * CH + hd * HDIM;
  #pragma unroll
  for (int dh = -1; dh <= 1; dh++) {
    #pragma unroll
    for (int dw = -1; dw <= 1; dw++) {
      bool valid = ((unsigned)(h + dh) < HH) && ((unsigned)(wx + dw) < WW);
      if (valid) {
        const bf16* vp = vbase + (dh * WW + dw) * CH;
        const int tap = (dh + 1) * 3 + (dw + 1);
        #pragma unroll
        for (int g = 0; g < 8; g++) {
          float4 vv = ld4(vp + g * 4);
          le[g * 4 + 0] += vv.x * wst[tap][g * 4 + 0];
          le[g * 4 + 1] += vv.y * wst[tap][g * 4 + 1];
          le[g * 4 + 2] += vv.z * wst[tap][g * 4 + 2];
          le[g * 4 + 3] += vv.w * wst[tap][g * 4 + 3];
        }
      }
    }
  }
  bf16* op = attn + (size_t)pix * CH + hd * HDIM;
  #pragma unroll
  for (int i = 0; i < 4; i++) {
    __align__(16) bf16 tmp[8];
    #pragma unroll
    for (int j = 0; j < 8; j++) tmp[j] = f2b(o[i * 8 + j] * zi + le[i * 8 + j]);
    *(short8*)&op[i * 8] = *(const short8*)tmp;
  }
}

extern "C" void kernel_launch(void* const* d_in, const int* in_sizes, int n_in,
                              void* d_out, int out_size, void* d_ws, size_t ws_size,
                              hipStream_t stream) {
  const float* x = (const float*)d_in[0];
  const float* cpe1w = (const float*)d_in[1];
  const float* cpe1b = (const float*)d_in[2];
  const float* n1w = (const float*)d_in[3];
  const float* n1b = (const float*)d_in[4];
  const float* apw = (const float*)d_in[5];
  const float* apb = (const float*)d_in[6];
  const float* ipw = (const float*)d_in[7];
  const float* ipb = (const float*)d_in[8];
  const float* dwcw = (const float*)d_in[9];
  const float* dwcb = (const float*)d_in[10];
  const float* qkw = (const float*)d_in[11];
  const float* qkb = (const float*)d_in[12];
  const float* lepw = (const float*)d_in[13];
  const float* lepb = (const float*)d_in[14];
  const float* opw = (const float*)d_in[15];
  const float* opb = (const float*)d_in[16];
  const float* cpe2w = (const float*)d_in[17];
  const float* cpe2b = (const float*)d_in[18];
  const float* n2w = (const float*)d_in[19];
  const float* n2b = (const float*)d_in[20];
  const float* f1w = (const float*)d_in[21];
  const float* f1b = (const float*)d_in[22];
  const float* f2w = (const float*)d_in[23];
  const float* f2b = (const float*)d_in[24];
  float* out = (float*)d_out;

  float* ws = (float*)d_ws;
  const size_t S = (size_t)NPIX * CH;
  float* FA = ws;                       // fp32: x NHWC -> (bf16 k/attn scratch) -> x3 -> final
  float* FB = ws + S;                   // fp32: x1 -> (bf16 MLP hidden stripes)
  bf16* barena = (bf16*)(ws + 2 * S);
  bf16* b0 = barena;                    // y -> t/v -> y4
  bf16* b1 = barena + S;                // act_res
  bf16* b2 = barena + 2 * S;            // y2 -> q -> x2
  bf16* KB = (bf16*)FA;                 // k, then attn (FA dead between cpe1 and cpe2)
  float* COS = ws + 2 * S + 3 * S / 2;
  float* SIN = COS + (size_t)NPAIR * HWSZ;
  float* KV = SIN + (size_t)NPAIR * HWSZ;
  float* KM = KV + BQ * NHEADS * HDIM * HDIM;
  bf16* HIDB = (bf16*)FB;

  dim3 tb(32, 8);
  // 1. transpose input NCHW -> NHWC fp32
  k_transpose_in<<<dim3(6, 128, BQ), tb, 0, stream>>>(x, FA);
  // 2. rope tables [pair][hw]
  k_rope<<<dim3(NPAIR * HWSZ / 256), dim3(256), 0, stream>>>(COS, SIN);
  // 3. x1 = x + cpe1(x); y = LN1(x1)   [fused]
  k_cpe_ln<float><<<dim3(NPIX / 4), dim3(192), 0, stream>>>(FA, cpe1w, cpe1b, n1w, n1b, FB, b0);
  // 4. act_res = silu(act_proj(y)); y2 = in_proj(y)
  k_gemm_dual<1, 0, 0><<<dim3(NPIX / 128, 6), dim3(256), 0, stream>>>(
      b0, apw, apb, ipw, ipb, b1, b2, nullptr, CH);
  // 5. t = v = silu(dwc(y2))
  k_dwconv4<<<dim3(NPIX * 48 / 256), dim3(256), 0, stream>>>(b2, dwcw, dwcb, b0);
  // 6. q,k = elu(t @ qk_w^T + qk_b)+1 ; kmean fused into k epilogue
  hipMemsetAsync(KM, 0, (size_t)BQ * CH * sizeof(float), stream);
  k_gemm_dual<2, 2, 1><<<dim3(NPIX / 128, 6), dim3(256), 0, stream>>>(
      b0, qkw, qkb, qkw + CH * CH, qkb + CH, b2, KB, KM, CH);
  // 7. kv accumulate (fused rope, 512 rows/block)
  hipMemsetAsync(KV, 0, (size_t)BQ * NHEADS * HDIM * HDIM * sizeof(float), stream);
  k_kv<<<dim3(BQ * NHEADS, 8), dim3(256), 0, stream>>>(KB, b0, COS, SIN, KV);
  // 8. attn = (q_rope @ kv) * z + lepe(v)  -> KB (k dead)
  k_attn<<<dim3(HWSZ / 256, NHEADS, BQ), dim3(256), 0, stream>>>(
      b2, b0, KV, KM, COS, SIN, lepw, lepb, KB);
  // 9. x2 = x1 + out_proj(attn * act_res)  -> b2 (bf16)
  k_gemm<0, 1, 1, bf16><<<dim3(NPIX / 128, 3), dim3(256), 0, stream>>>(
      KB, b1, opw, opb, FB, b2, NPIX, CH, CH);
  // 10. x3 = x2 + cpe2(x2); y4 = LN2(x3)   [fused]
  k_cpe_ln<bf16><<<dim3(NPIX / 4), dim3(192), 0, stream>>>(b2, cpe2w, cpe2b, n2w, n2b, FA, b0);
  // 11. MLP in 2 stripes; hidden bf16 stripe lives in FB (x1 dead)
  for (int s = 0; s < 2; s++) {
    size_t off = (size_t)s * (NPIX / 2) * CH;
    k_gemm<3, 0, 0, bf16><<<dim3((NPIX / 2) / 128, HID / 64), dim3(256), 0, stream>>>(
        b0 + off, (const bf16*)nullptr, f1w, f1b, (const float*)nullptr, HIDB, NPIX / 2, HID, CH);
    k_gemm<0, 0, 1, float><<<dim3((NPIX / 2) / 128, 3), dim3(256), 0, stream>>>(
        HIDB, (const bf16*)nullptr, f2w, f2b, FA + off, FA + off, NPIX / 2, CH, HID);
  }
  // 12. final transpose NHWC fp32 -> NCHW fp32
  k_transpose_out<<<dim3(6, 128, BQ), tb, 0, stream>>>(FA, out);
}

// Round 7
// 703.896 us; speedup vs baseline: 1.8909x; 1.8909x over previous
//
#include <hip/hip_runtime.h>
#include <hip/hip_bf16.h>

#define BQ 16
#define CH 192
#define HH 64
#define WW 64
#define HWSZ 4096
#define NPIX 65536
#define NHEADS 6
#define HDIM 32
#define NPAIR 96
#define KMAXR 48
#define HID 768

typedef __hip_bfloat16 bf16;
typedef __attribute__((ext_vector_type(8))) short short8;
typedef __attribute__((ext_vector_type(4))) float floatx4;

static __device__ __forceinline__ float b2f(bf16 v) { return __bfloat162float(v); }
static __device__ __forceinline__ bf16 f2b(float v) { return __float2bfloat16(v); }

static __device__ __forceinline__ float4 ld4(const float* p) { return *(const float4*)p; }
static __device__ __forceinline__ float4 ld4(const bf16* p) {
  uint2 u = *(const uint2*)p;
  return make_float4(__uint_as_float(u.x << 16), __uint_as_float(u.x & 0xffff0000u),
                     __uint_as_float(u.y << 16), __uint_as_float(u.y & 0xffff0000u));
}

template <int ACT>
static __device__ __forceinline__ float actf(float v) {
  if (ACT == 1) return v / (1.f + expf(-v));                               // silu
  if (ACT == 2) return (v > 0.f) ? v + 1.f : expf(v);                      // elu+1
  if (ACT == 3) return 0.5f * v * (1.f + erff(v * 0.70710678118654752f));  // gelu
  return v;
}
static __device__ __forceinline__ void stv(float* p, float v) { *p = v; }
static __device__ __forceinline__ void stv(bf16* p, float v) { *p = __float2bfloat16(v); }

// ---------------- transpose NCHW -> NHWC (fp32) ----------------
__global__ __launch_bounds__(256) void k_transpose_in(const float* __restrict__ in,
                                                      float* __restrict__ out) {
  __shared__ float tile[32][33];
  int c0 = blockIdx.x * 32, hw0 = blockIdx.y * 32, b = blockIdx.z;
  int tx = threadIdx.x, ty = threadIdx.y;
  const float* src = in + (size_t)b * CH * HWSZ;
  #pragma unroll
  for (int j = 0; j < 32; j += 8)
    tile[ty + j][tx] = src[(size_t)(c0 + ty + j) * HWSZ + hw0 + tx];
  __syncthreads();
  float* dst = out + (size_t)b * HWSZ * CH;
  #pragma unroll
  for (int j = 0; j < 32; j += 8)
    dst[(size_t)(hw0 + ty + j) * CH + c0 + tx] = tile[tx][ty + j];
}

// ---------------- transpose NHWC -> NCHW (fp32) ----------------
__global__ __launch_bounds__(256) void k_transpose_out(const float* __restrict__ in,
                                                       float* __restrict__ out) {
  __shared__ float tile[32][33];
  int c0 = blockIdx.x * 32, hw0 = blockIdx.y * 32, b = blockIdx.z;
  int tx = threadIdx.x, ty = threadIdx.y;
  const float* src = in + (size_t)b * HWSZ * CH;
  #pragma unroll
  for (int j = 0; j < 32; j += 8)
    tile[ty + j][tx] = src[(size_t)(hw0 + ty + j) * CH + c0 + tx];
  __syncthreads();
  float* dst = out + (size_t)b * CH * HWSZ;
  #pragma unroll
  for (int j = 0; j < 32; j += 8)
    dst[(size_t)(c0 + ty + j) * HWSZ + hw0 + tx] = tile[tx][ty + j];
}

// ---------------- RoPE tables, layout [pair][hw] ----------------
__global__ __launch_bounds__(256) void k_rope(float* __restrict__ cosT, float* __restrict__ sinT) {
  int i = blockIdx.x * 256 + threadIdx.x;
  if (i >= NPAIR * HWSZ) return;
  int hw = i & (HWSZ - 1);
  int p = i >> 12;
  int h = hw >> 6, w = hw & 63;
  int j = (p < KMAXR) ? p : p - KMAXR;
  float theta = powf(10000.f, -(float)j / (float)KMAXR);
  float pos = (p < KMAXR) ? (float)h : (float)w;
  float ang = pos * theta;
  cosT[i] = cosf(ang);
  sinT[i] = sinf(ang);
}

// ---------------- fused dwconv(residual) + LayerNorm ----------------
// block = 4 pixels x 48 channel-groups (4ch each), 192 threads.
template <typename TI>
__global__ __launch_bounds__(192) void k_cpe_ln(const TI* __restrict__ in,
                                                const float* __restrict__ w,
                                                const float* __restrict__ bias,
                                                const float* __restrict__ g,
                                                const float* __restrict__ bt,
                                                float* __restrict__ x1o,
                                                bf16* __restrict__ yo) {
  __shared__ float sred[192], ssred[192];
  int t = threadIdx.x;
  int cg = t % 48, pl = t / 48;
  int pix = blockIdx.x * 4 + pl;
  int hw = pix & (HWSZ - 1);
  int h = hw >> 6, wx = hw & 63;
  int c0 = cg * 4;
  float4 w4[9];
  #pragma unroll
  for (int i = 0; i < 9; i++) w4[i] = ld4(w + c0 * 9 + i * 4);
  float4 bi = ld4(bias + c0);
  float acc0 = bi.x, acc1 = bi.y, acc2 = bi.z, acc3 = bi.w;
  float4 ctr;
  const TI* base = in + (size_t)pix * CH + c0;
  #pragma unroll
  for (int dh = -1; dh <= 1; dh++) {
    #pragma unroll
    for (int dw = -1; dw <= 1; dw++) {
      bool v = ((unsigned)(h + dh) < HH) && ((unsigned)(wx + dw) < WW);
      float4 tv = v ? ld4(base + (dh * WW + dw) * CH) : make_float4(0, 0, 0, 0);
      if (dh == 0 && dw == 0) ctr = tv;
      const int tap = (dh + 1) * 3 + (dw + 1);
      #define WX(j) (((const float*)w4)[(j) * 9 + tap])
      acc0 += tv.x * WX(0);
      acc1 += tv.y * WX(1);
      acc2 += tv.z * WX(2);
      acc3 += tv.w * WX(3);
      #undef WX
    }
  }
  float x0 = ctr.x + acc0, x1 = ctr.y + acc1, x2 = ctr.z + acc2, x3 = ctr.w + acc3;
  *(float4*)&x1o[(size_t)pix * CH + c0] = make_float4(x0, x1, x2, x3);
  sred[t] = x0 + x1 + x2 + x3;
  ssred[t] = x0 * x0 + x1 * x1 + x2 * x2 + x3 * x3;
  __syncthreads();
  float S = 0.f, SS = 0.f;
  int rb = pl * 48;
  #pragma unroll
  for (int i = 0; i < 48; i++) { S += sred[rb + i]; SS += ssred[rb + i]; }
  float mu = S * (1.f / CH);
  float inv = rsqrtf(SS * (1.f / CH) - mu * mu + 1e-5f);
  float4 gg = ld4(g + c0);
  float4 bb = ld4(bt + c0);
  __align__(8) bf16 tmp[4] = {f2b((x0 - mu) * inv * gg.x + bb.x),
                              f2b((x1 - mu) * inv * gg.y + bb.y),
                              f2b((x2 - mu) * inv * gg.z + bb.z),
                              f2b((x3 - mu) * inv * gg.w + bb.w)};
  *(uint2*)&yo[(size_t)pix * CH + c0] = *(uint2*)tmp;
}

// ---------------- vectorized dwconv, bf16 in/out, 4ch per thread ----------------
// MODE 1: out = silu(conv+bias)   MODE 2: out += conv+bias
template <int MODE>
__global__ __launch_bounds__(256) void k_dwconv4(const bf16* __restrict__ in,
                                                 const float* __restrict__ w,
                                                 const float* __restrict__ bias,
                                                 bf16* __restrict__ out) {
  int id = blockIdx.x * 256 + threadIdx.x;  // NPIX*48
  int cg = id % 48, pix = id / 48;
  int hw = pix & (HWSZ - 1);
  int h = hw >> 6, wx = hw & 63;
  int c0 = cg * 4;
  float4 w4[9];
  #pragma unroll
  for (int i = 0; i < 9; i++) w4[i] = ld4(w + c0 * 9 + i * 4);
  float4 bi = ld4(bias + c0);
  float acc0 = bi.x, acc1 = bi.y, acc2 = bi.z, acc3 = bi.w;
  const bf16* base = in + (size_t)pix * CH + c0;
  #pragma unroll
  for (int dh = -1; dh <= 1; dh++) {
    #pragma unroll
    for (int dw = -1; dw <= 1; dw++) {
      bool v = ((unsigned)(h + dh) < HH) && ((unsigned)(wx + dw) < WW);
      float4 tv = v ? ld4(base + (dh * WW + dw) * CH) : make_float4(0, 0, 0, 0);
      const int tap = (dh + 1) * 3 + (dw + 1);
      #define WX(j) (((const float*)w4)[(j) * 9 + tap])
      acc0 += tv.x * WX(0);
      acc1 += tv.y * WX(1);
      acc2 += tv.z * WX(2);
      acc3 += tv.w * WX(3);
      #undef WX
    }
  }
  bf16* op = out + (size_t)pix * CH + c0;
  if (MODE == 1) {
    acc0 = acc0 / (1.f + expf(-acc0));
    acc1 = acc1 / (1.f + expf(-acc1));
    acc2 = acc2 / (1.f + expf(-acc2));
    acc3 = acc3 / (1.f + expf(-acc3));
  } else {
    float4 cur = ld4(op);
    acc0 += cur.x; acc1 += cur.y; acc2 += cur.z; acc3 += cur.w;
  }
  __align__(8) bf16 tmp[4] = {f2b(acc0), f2b(acc1), f2b(acc2), f2b(acc3)};
  *(uint2*)op = *(uint2*)tmp;
}

// ---------------- MFMA bf16 GEMM: tile 128x64, BK=32 ----------------
template <int ACT, int MULA, int RES, typename TO>
__global__ __launch_bounds__(256) void k_gemm(const bf16* __restrict__ A,
                                              const bf16* __restrict__ A2,
                                              const float* __restrict__ Wt,
                                              const float* __restrict__ bias,
                                              const float* __restrict__ Rsd,
                                              TO* __restrict__ Cout,
                                              int M, int N, int K) {
  __shared__ bf16 As[128][40];
  __shared__ bf16 Bs[64][40];
  int t = threadIdx.x;
  int wave = t >> 6, lane = t & 63;
  int quad = lane >> 4, l16 = lane & 15;
  int m0 = blockIdx.x * 128, n0 = blockIdx.y * 64;
  floatx4 acc[2][4] = {};
  for (int k0 = 0; k0 < K; k0 += 32) {
    #pragma unroll
    for (int i = 0; i < 2; i++) {
      int idx = t + i * 256;
      int m = idx >> 2, kk = (idx & 3) * 8;
      const bf16* pa = &A[(size_t)(m0 + m) * K + k0 + kk];
      if (!MULA) {
        *(short8*)&As[m][kk] = *(const short8*)pa;
      } else {
        const bf16* pb = &A2[(size_t)(m0 + m) * K + k0 + kk];
        __align__(16) bf16 tmp[8];
        #pragma unroll
        for (int j = 0; j < 8; j++) tmp[j] = f2b(b2f(pa[j]) * b2f(pb[j]));
        *(short8*)&As[m][kk] = *(const short8*)tmp;
      }
    }
    #pragma unroll
    for (int i = 0; i < 2; i++) {
      int idx = t + i * 256;
      int n = idx >> 3, kk = (idx & 7) * 4;
      float4 v = *(const float4*)&Wt[(size_t)(n0 + n) * K + k0 + kk];
      __align__(8) bf16 tmp[4] = {f2b(v.x), f2b(v.y), f2b(v.z), f2b(v.w)};
      *(uint2*)&Bs[n][kk] = *(uint2*)tmp;
    }
    __syncthreads();
    short8 af[2], bfr[4];
    #pragma unroll
    for (int i = 0; i < 2; i++)
      af[i] = *(const short8*)&As[wave * 32 + i * 16 + l16][quad * 8];
    #pragma unroll
    for (int j = 0; j < 4; j++)
      bfr[j] = *(const short8*)&Bs[j * 16 + l16][quad * 8];
    #pragma unroll
    for (int i = 0; i < 2; i++)
      #pragma unroll
      for (int j = 0; j < 4; j++)
        acc[i][j] = __builtin_amdgcn_mfma_f32_16x16x32_bf16(af[i], bfr[j], acc[i][j], 0, 0, 0);
    __syncthreads();
  }
  #pragma unroll
  for (int i = 0; i < 2; i++) {
    #pragma unroll
    for (int j = 0; j < 4; j++) {
      int n = n0 + j * 16 + l16;
      float bn = bias[n];
      #pragma unroll
      for (int r = 0; r < 4; r++) {
        int m = m0 + wave * 32 + i * 16 + quad * 4 + r;
        float v = actf<ACT>(acc[i][j][r] + bn);
        if (RES) v += Rsd[(size_t)m * N + n];
        stv(&Cout[(size_t)m * N + n], v);
      }
    }
  }
}

// dual-output GEMM: N=384 as two 192 halves; optional fused column-mean of half B.
template <int ACTA, int ACTB, int KMEAN>
__global__ __launch_bounds__(256) void k_gemm_dual(const bf16* __restrict__ A,
                                                   const float* __restrict__ WtA,
                                                   const float* __restrict__ biasA,
                                                   const float* __restrict__ WtB,
                                                   const float* __restrict__ biasB,
                                                   bf16* __restrict__ OutA,
                                                   bf16* __restrict__ OutB,
                                                   float* __restrict__ KM,
                                                   int K) {
  __shared__ bf16 As[128][40];
  __shared__ bf16 Bs[64][40];
  __shared__ float colsum[64];
  int t = threadIdx.x;
  int wave = t >> 6, lane = t & 63;
  int quad = lane >> 4, l16 = lane & 15;
  int m0 = blockIdx.x * 128, n0 = blockIdx.y * 64;
  int half = n0 >= 192;
  int n0l = half ? n0 - 192 : n0;
  const float* Wt = half ? WtB : WtA;
  const float* bias = half ? biasB : biasA;
  bf16* Out = half ? OutB : OutA;
  if (KMEAN && half && t < 64) colsum[t] = 0.f;
  floatx4 acc[2][4] = {};
  for (int k0 = 0; k0 < K; k0 += 32) {
    #pragma unroll
    for (int i = 0; i < 2; i++) {
      int idx = t + i * 256;
      int m = idx >> 2, kk = (idx & 3) * 8;
      *(short8*)&As[m][kk] = *(const short8*)&A[(size_t)(m0 + m) * K + k0 + kk];
    }
    #pragma unroll
    for (int i = 0; i < 2; i++) {
      int idx = t + i * 256;
      int n = idx >> 3, kk = (idx & 7) * 4;
      float4 v = *(const float4*)&Wt[(size_t)(n0l + n) * K + k0 + kk];
      __align__(8) bf16 tmp[4] = {f2b(v.x), f2b(v.y), f2b(v.z), f2b(v.w)};
      *(uint2*)&Bs[n][kk] = *(uint2*)tmp;
    }
    __syncthreads();
    short8 af[2], bfr[4];
    #pragma unroll
    for (int i = 0; i < 2; i++)
      af[i] = *(const short8*)&As[wave * 32 + i * 16 + l16][quad * 8];
    #pragma unroll
    for (int j = 0; j < 4; j++)
      bfr[j] = *(const short8*)&Bs[j * 16 + l16][quad * 8];
    #pragma unroll
    for (int i = 0; i < 2; i++)
      #pragma unroll
      for (int j = 0; j < 4; j++)
        acc[i][j] = __builtin_amdgcn_mfma_f32_16x16x32_bf16(af[i], bfr[j], acc[i][j], 0, 0, 0);
    __syncthreads();
  }
  #pragma unroll
  for (int j = 0; j < 4; j++) {
    int nl = n0l + j * 16 + l16;
    float bn = bias[nl];
    float csum = 0.f;
    #pragma unroll
    for (int i = 0; i < 2; i++) {
      #pragma unroll
      for (int r = 0; r < 4; r++) {
        int m = m0 + wave * 32 + i * 16 + quad * 4 + r;
        float v = half ? actf<ACTB>(acc[i][j][r] + bn) : actf<ACTA>(acc[i][j][r] + bn);
        if (KMEAN && half) csum += v;
        Out[(size_t)m * CH + nl] = f2b(v);
      }
    }
    if (KMEAN && half) atomicAdd(&colsum[j * 16 + l16], csum);
  }
  if (KMEAN && half) {
    __syncthreads();
    if (t < 64) {
      int b = m0 >> 12;
      atomicAdd(&KM[b * CH + n0l + t], colsum[t] * (1.f / 4096.f));
    }
  }
}

// ---------------- kv: fused-rope staging, 512 rows/block, bf16 LDS ----------------
__global__ __launch_bounds__(256) void k_kv(const bf16* __restrict__ k,
                                            const bf16* __restrict__ v,
                                            const float* __restrict__ cosT,
                                            const float* __restrict__ sinT,
                                            float* __restrict__ kv) {
  int bh = blockIdx.x;
  int b = bh / NHEADS, hd = bh % NHEADS;
  int chunk0 = blockIdx.y * 512;
  __shared__ bf16 ks[256][40];
  __shared__ bf16 vs[256][40];
  int t = threadIdx.x;
  int d = t >> 3;
  int e0 = (t & 7) * 4;
  float a0 = 0, a1 = 0, a2 = 0, a3 = 0;
  for (int sub = 0; sub < 2; sub++) {
    int n0 = chunk0 + sub * 256;
    #pragma unroll
    for (int it = 0; it < 4; it++) {
      int idx = t + it * 256;            // 0..1023
      int row = idx >> 2, c0 = (idx & 3) * 8;
      int n = n0 + row;
      size_t gi = ((size_t)(b * HWSZ + n)) * CH + hd * HDIM + c0;
      *(short8*)&vs[row][c0] = *(const short8*)&v[gi];
      float4 klo = ld4(&k[gi]);
      float4 khi = ld4(&k[gi + 4]);
      int prb = hd * 16 + (c0 >> 1);
      float cs0 = cosT[(size_t)(prb + 0) * HWSZ + n];
      float sn0 = sinT[(size_t)(prb + 0) * HWSZ + n];
      float cs1 = cosT[(size_t)(prb + 1) * HWSZ + n];
      float sn1 = sinT[(size_t)(prb + 1) * HWSZ + n];
      float cs2 = cosT[(size_t)(prb + 2) * HWSZ + n];
      float sn2 = sinT[(size_t)(prb + 2) * HWSZ + n];
      float cs3 = cosT[(size_t)(prb + 3) * HWSZ + n];
      float sn3 = sinT[(size_t)(prb + 3) * HWSZ + n];
      __align__(16) bf16 kt[8];
      kt[0] = f2b(klo.x * cs0 - klo.y * sn0);
      kt[1] = f2b(klo.x * sn0 + klo.y * cs0);
      kt[2] = f2b(klo.z * cs1 - klo.w * sn1);
      kt[3] = f2b(klo.z * sn1 + klo.w * cs1);
      kt[4] = f2b(khi.x * cs2 - khi.y * sn2);
      kt[5] = f2b(khi.x * sn2 + khi.y * cs2);
      kt[6] = f2b(khi.z * cs3 - khi.w * sn3);
      kt[7] = f2b(khi.z * sn3 + khi.w * cs3);
      *(short8*)&ks[row][c0] = *(const short8*)kt;
    }
    __syncthreads();
    #pragma unroll 4
    for (int i = 0; i < 256; i++) {
      float kd = b2f(ks[i][d]);
      float4 vv = ld4(&vs[i][e0]);
      a0 += kd * vv.x;
      a1 += kd * vv.y;
      a2 += kd * vv.z;
      a3 += kd * vv.w;
    }
    __syncthreads();
  }
  float* dst = kv + (size_t)bh * (HDIM * HDIM) + d * HDIM + e0;
  const float sc = 1.f / 4096.f;
  atomicAdd(dst + 0, a0 * sc);
  atomicAdd(dst + 1, a1 * sc);
  atomicAdd(dst + 2, a2 * sc);
  atomicAdd(dst + 3, a3 * sc);
}

// ---------------- attn: per (pix-chunk, head, batch); kv in LDS (lean, no lepe) -------
__global__ __launch_bounds__(256) void k_attn(const bf16* __restrict__ q,
                                              const float* __restrict__ kv,
                                              const float* __restrict__ kmean,
                                              const float* __restrict__ cosT,
                                              const float* __restrict__ sinT,
                                              bf16* __restrict__ attn) {
  int hd = blockIdx.y, b = blockIdx.z;
  int hw = blockIdx.x * 256 + threadIdx.x;
  int bh = b * NHEADS + hd;
  __shared__ float kvs[32][33];
  __shared__ float kms[32];
  #pragma unroll
  for (int i = 0; i < 4; i++) {
    int idx = threadIdx.x + i * 256;
    kvs[idx >> 5][idx & 31] = kv[(size_t)bh * 1024 + idx];
  }
  if (threadIdx.x < 32) kms[threadIdx.x] = kmean[b * CH + hd * HDIM + threadIdx.x];
  __syncthreads();
  int pix = b * HWSZ + hw;
  const bf16* qp = q + (size_t)pix * CH + hd * HDIM;
  float qv[32];
  #pragma unroll
  for (int i = 0; i < 32; i++) qv[i] = b2f(qp[i]);
  float z = 1e-6f;
  #pragma unroll
  for (int d = 0; d < 32; d++) z += qv[d] * kms[d];
  float o[32] = {};
  #pragma unroll
  for (int p = 0; p < 16; p++) {
    float cs = cosT[(size_t)(hd * 16 + p) * HWSZ + hw];
    float sn = sinT[(size_t)(hd * 16 + p) * HWSZ + hw];
    float re = qv[2 * p], im = qv[2 * p + 1];
    float qr = re * cs - im * sn;
    float qi = re * sn + im * cs;
    #pragma unroll
    for (int e = 0; e < 32; e++)
      o[e] += qr * kvs[2 * p][e] + qi * kvs[2 * p + 1][e];
  }
  float zi = 1.f / z;
  bf16* op = attn + (size_t)pix * CH + hd * HDIM;
  #pragma unroll
  for (int i = 0; i < 4; i++) {
    __align__(16) bf16 tmp[8];
    #pragma unroll
    for (int j = 0; j < 8; j++) tmp[j] = f2b(o[i * 8 + j] * zi);
    *(short8*)&op[i * 8] = *(const short8*)tmp;
  }
}

extern "C" void kernel_launch(void* const* d_in, const int* in_sizes, int n_in,
                              void* d_out, int out_size, void* d_ws, size_t ws_size,
                              hipStream_t stream) {
  const float* x = (const float*)d_in[0];
  const float* cpe1w = (const float*)d_in[1];
  const float* cpe1b = (const float*)d_in[2];
  const float* n1w = (const float*)d_in[3];
  const float* n1b = (const float*)d_in[4];
  const float* apw = (const float*)d_in[5];
  const float* apb = (const float*)d_in[6];
  const float* ipw = (const float*)d_in[7];
  const float* ipb = (const float*)d_in[8];
  const float* dwcw = (const float*)d_in[9];
  const float* dwcb = (const float*)d_in[10];
  const float* qkw = (const float*)d_in[11];
  const float* qkb = (const float*)d_in[12];
  const float* lepw = (const float*)d_in[13];
  const float* lepb = (const float*)d_in[14];
  const float* opw = (const float*)d_in[15];
  const float* opb = (const float*)d_in[16];
  const float* cpe2w = (const float*)d_in[17];
  const float* cpe2b = (const float*)d_in[18];
  const float* n2w = (const float*)d_in[19];
  const float* n2b = (const float*)d_in[20];
  const float* f1w = (const float*)d_in[21];
  const float* f1b = (const float*)d_in[22];
  const float* f2w = (const float*)d_in[23];
  const float* f2b = (const float*)d_in[24];
  float* out = (float*)d_out;

  float* ws = (float*)d_ws;
  const size_t S = (size_t)NPIX * CH;
  float* FA = ws;                       // fp32: x NHWC -> (bf16 k/attn scratch) -> x3 -> final
  float* FB = ws + S;                   // fp32: x1 -> (bf16 MLP hidden stripes)
  bf16* barena = (bf16*)(ws + 2 * S);
  bf16* b0 = barena;                    // y -> t/v -> y4
  bf16* b1 = barena + S;                // act_res
  bf16* b2 = barena + 2 * S;            // y2 -> q -> x2
  bf16* KB = (bf16*)FA;                 // k, then attn (FA dead between cpe1 and cpe2)
  float* COS = ws + 2 * S + 3 * S / 2;
  float* SIN = COS + (size_t)NPAIR * HWSZ;
  float* KV = SIN + (size_t)NPAIR * HWSZ;
  float* KM = KV + BQ * NHEADS * HDIM * HDIM;
  bf16* HIDB = (bf16*)FB;

  dim3 tb(32, 8);
  // 1. transpose input NCHW -> NHWC fp32
  k_transpose_in<<<dim3(6, 128, BQ), tb, 0, stream>>>(x, FA);
  // 2. rope tables [pair][hw]
  k_rope<<<dim3(NPAIR * HWSZ / 256), dim3(256), 0, stream>>>(COS, SIN);
  // 3. x1 = x + cpe1(x); y = LN1(x1)   [fused]
  k_cpe_ln<float><<<dim3(NPIX / 4), dim3(192), 0, stream>>>(FA, cpe1w, cpe1b, n1w, n1b, FB, b0);
  // 4. act_res = silu(act_proj(y)); y2 = in_proj(y)
  k_gemm_dual<1, 0, 0><<<dim3(NPIX / 128, 6), dim3(256), 0, stream>>>(
      b0, apw, apb, ipw, ipb, b1, b2, nullptr, CH);
  // 5. t = v = silu(dwc(y2))
  k_dwconv4<1><<<dim3(NPIX * 48 / 256), dim3(256), 0, stream>>>(b2, dwcw, dwcb, b0);
  // 6. q,k = elu(t @ qk_w^T + qk_b)+1 ; kmean fused into k epilogue
  hipMemsetAsync(KM, 0, (size_t)BQ * CH * sizeof(float), stream);
  k_gemm_dual<2, 2, 1><<<dim3(NPIX / 128, 6), dim3(256), 0, stream>>>(
      b0, qkw, qkb, qkw + CH * CH, qkb + CH, b2, KB, KM, CH);
  // 7. kv accumulate (fused rope, 512 rows/block)
  hipMemsetAsync(KV, 0, (size_t)BQ * NHEADS * HDIM * HDIM * sizeof(float), stream);
  k_kv<<<dim3(BQ * NHEADS, 8), dim3(256), 0, stream>>>(KB, b0, COS, SIN, KV);
  // 8. attn = (q_rope @ kv) * z  -> KB (k dead)
  k_attn<<<dim3(HWSZ / 256, NHEADS, BQ), dim3(256), 0, stream>>>(b2, KV, KM, COS, SIN, KB);
  // 9. attn += lepe(v)
  k_dwconv4<2><<<dim3(NPIX * 48 / 256), dim3(256), 0, stream>>>(b0, lepw, lepb, KB);
  // 10. x2 = x1 + out_proj(attn * act_res)  -> b2 (bf16)
  k_gemm<0, 1, 1, bf16><<<dim3(NPIX / 128, 3), dim3(256), 0, stream>>>(
      KB, b1, opw, opb, FB, b2, NPIX, CH, CH);
  // 11. x3 = x2 + cpe2(x2); y4 = LN2(x3)   [fused]
  k_cpe_ln<bf16><<<dim3(NPIX / 4), dim3(192), 0, stream>>>(b2, cpe2w, cpe2b, n2w, n2b, FA, b0);
  // 12. MLP in 2 stripes; hidden bf16 stripe lives in FB (x1 dead)
  for (int s = 0; s < 2; s++) {
    size_t off = (size_t)s * (NPIX / 2) * CH;
    k_gemm<3, 0, 0, bf16><<<dim3((NPIX / 2) / 128, HID / 64), dim3(256), 0, stream>>>(
        b0 + off, (const bf16*)nullptr, f1w, f1b, (const float*)nullptr, HIDB, NPIX / 2, HID, CH);
    k_gemm<0, 0, 1, float><<<dim3((NPIX / 2) / 128, 3), dim3(256), 0, stream>>>(
        HIDB, (const bf16*)nullptr, f2w, f2b, FA + off, FA + off, NPIX / 2, CH, HID);
  }
  // 13. final transpose NHWC fp32 -> NCHW fp32
  k_transpose_out<<<dim3(6, 128, BQ), tb, 0, stream>>>(FA, out);
}